// Round 5
// baseline (4211.659 us; speedup 1.0000x reference)
//
#include <hip/hip_runtime.h>

// ---------------------------------------------------------------------------
// Stacked tanh-RNN (S=128,B=128,V=10000,H=E=512,L=2) for MI355X.
// Decomposition:
//   x = emb[tok]*sqrt(E)                      -> k_embed (split hi/lo bf16)
//   P0 = x @ W0x^T + b0                       -> gemm128<split> (3-term MFMA)
//   h0(t) = tanh(h0(t-1) @ W0h^T + P0[t])     -> rnn_chain (persistent, barrier/step)
//   Z  = h0seq @ W1x^T + bl                   -> gemm128<split>
//   h1(t) = tanh(h1(t-1) @ W1h^T + Z[t])      -> rnn_chain
//   logits = h1seq @ Wout^T + bout            -> gemm128<single bf16>
// Split-bf16 (hi/lo) 3-term MFMA gives ~fp32 accuracy for everything feeding
// the recurrence; single bf16 only on the final 168-GF logits GEMM.
// ---------------------------------------------------------------------------

typedef __bf16 bf16x8 __attribute__((ext_vector_type(8)));
typedef float  f32x4  __attribute__((ext_vector_type(8/2)));

constexpr int SS = 128, BB = 128, VV = 10000, HH = 512;
constexpr int SB  = SS * BB;                 // 16384
constexpr int BH  = BB * HH;                 // 65536
constexpr size_t SBH = (size_t)SB * HH;      // 8,388,608
constexpr size_t SBV = (size_t)SB * VV;      // 163,840,000
constexpr int VP = 10112;                    // V padded to 79*128
constexpr size_t HSLOT_E = (size_t)(SS + 1) * BH;   // h sequence incl. init slot
constexpr size_t HSLOT_B = HSLOT_E * 2;

// workspace byte offsets
constexpr size_t O_CNT    = 0;               // 256 ints (barrier counters)
constexpr size_t WMATB    = (size_t)512 * 512 * 2;
constexpr size_t O_W0H_HI = 1024;
constexpr size_t O_W0H_LO = O_W0H_HI + WMATB;
constexpr size_t O_W0X_HI = O_W0H_LO + WMATB;
constexpr size_t O_W0X_LO = O_W0X_HI + WMATB;
constexpr size_t O_W1H_HI = O_W0X_LO + WMATB;
constexpr size_t O_W1H_LO = O_W1H_HI + WMATB;
constexpr size_t O_W1X_HI = O_W1H_LO + WMATB;
constexpr size_t O_W1X_LO = O_W1X_HI + WMATB;
constexpr size_t O_WOUT   = O_W1X_LO + WMATB;          // VP*512 bf16
constexpr size_t O_BOUT   = O_WOUT + (size_t)VP * 512 * 2;  // VP f32
constexpr size_t O_R1     = O_BOUT + (size_t)VP * 4;   // x_hi/x_lo, later Z (f32)
constexpr size_t O_R2     = O_R1 + SBH * 4;            // P0 (f32), later h1 hi/lo
constexpr size_t O_R3     = O_R2 + 2 * HSLOT_B;        // h0 hi/lo

__device__ __forceinline__ unsigned short f2bf(float f) {
  unsigned u = __builtin_bit_cast(unsigned, f);
  u += 0x7FFFu + ((u >> 16) & 1u);           // RNE
  return (unsigned short)(u >> 16);
}
__device__ __forceinline__ float bf2f(unsigned short h) {
  unsigned u = ((unsigned)h) << 16;
  return __builtin_bit_cast(float, u);
}
__device__ __forceinline__ f32x4 mfma16(bf16x8 a, bf16x8 b, f32x4 c) {
  return __builtin_amdgcn_mfma_f32_16x16x32_bf16(a, b, c, 0, 0, 0);
}

// ---------------------------------------------------------------------------
// Setup: weight splits, Wout bf16 (padded), bout padded, h0 slot0, counters.
// ---------------------------------------------------------------------------
__global__ __launch_bounds__(256) void k_setup(
    const float* __restrict__ hidden, const float* __restrict__ W0,
    const float* __restrict__ Wl, const float* __restrict__ Wout,
    const float* __restrict__ bout, char* __restrict__ ws)
{
  unsigned short* w0h_hi = (unsigned short*)(ws + O_W0H_HI);
  unsigned short* w0h_lo = (unsigned short*)(ws + O_W0H_LO);
  unsigned short* w0x_hi = (unsigned short*)(ws + O_W0X_HI);
  unsigned short* w0x_lo = (unsigned short*)(ws + O_W0X_LO);
  unsigned short* w1h_hi = (unsigned short*)(ws + O_W1H_HI);
  unsigned short* w1h_lo = (unsigned short*)(ws + O_W1H_LO);
  unsigned short* w1x_hi = (unsigned short*)(ws + O_W1X_HI);
  unsigned short* w1x_lo = (unsigned short*)(ws + O_W1X_LO);
  unsigned short* woutb  = (unsigned short*)(ws + O_WOUT);
  float* boutp = (float*)(ws + O_BOUT);
  unsigned short* h0hi = (unsigned short*)(ws + O_R3);
  unsigned short* h0lo = h0hi + HSLOT_E;
  int* cnt = (int*)(ws + O_CNT);

  const size_t NW = (size_t)512 * 1024;
  const size_t NWOUT = (size_t)VP * 512;
  const size_t TOT = 2 * NW + NWOUT + VP + BH + 256;
  for (size_t idx = (size_t)blockIdx.x * blockDim.x + threadIdx.x; idx < TOT;
       idx += (size_t)gridDim.x * blockDim.x) {
    size_t i = idx;
    if (i < 2 * NW) {
      bool first = (i < NW);
      size_t j = first ? i : i - NW;
      const float* srcm = first ? W0 : Wl;
      float v = srcm[j];
      unsigned short hb = f2bf(v);
      unsigned short lb = f2bf(v - bf2f(hb));
      int r = (int)(j >> 10), c = (int)(j & 1023);
      size_t d = ((size_t)r << 9) + (c & 511);
      if (c < 512) {
        if (first) { w0h_hi[d] = hb; w0h_lo[d] = lb; }
        else       { w1h_hi[d] = hb; w1h_lo[d] = lb; }
      } else {
        if (first) { w0x_hi[d] = hb; w0x_lo[d] = lb; }
        else       { w1x_hi[d] = hb; w1x_lo[d] = lb; }
      }
      continue;
    }
    i -= 2 * NW;
    if (i < NWOUT) {
      int r = (int)(i >> 9), c = (int)(i & 511);
      woutb[i] = (r < VV) ? f2bf(Wout[(size_t)r * 512 + c]) : (unsigned short)0;
      continue;
    }
    i -= NWOUT;
    if (i < (size_t)VP) { boutp[i] = (i < (size_t)VV) ? bout[i] : 0.0f; continue; }
    i -= VP;
    if (i < (size_t)BH) {   // layer-0 initial hidden -> h0 slot 0
      float v = hidden[i];
      unsigned short hb = f2bf(v);
      h0hi[i] = hb; h0lo[i] = f2bf(v - bf2f(hb));
      continue;
    }
    i -= BH;
    cnt[i] = 0;
  }
}

// layer-1 initial hidden -> h1 slot0 (runs after chain0; h1 aliases P0)
__global__ __launch_bounds__(256) void k_h1init(
    const float* __restrict__ hidden, unsigned short* __restrict__ h1hi,
    unsigned short* __restrict__ h1lo)
{
  int idx = blockIdx.x * 256 + threadIdx.x;
  float v = hidden[(size_t)BH + idx];
  unsigned short hb = f2bf(v);
  h1hi[idx] = hb; h1lo[idx] = f2bf(v - bf2f(hb));
}

// ---------------------------------------------------------------------------
// Embedding gather + scale, split into hi/lo bf16.
// ---------------------------------------------------------------------------
__global__ __launch_bounds__(256) void k_embed(
    const int* __restrict__ toks, const float* __restrict__ emb,
    unsigned short* __restrict__ xhi, unsigned short* __restrict__ xlo)
{
  const float scale = 22.62741699796952f;    // sqrt(512)
  size_t idx = (size_t)blockIdx.x * 256 + threadIdx.x;   // over SB*128 quads
  if (idx >= (size_t)SB * 128) return;
  int row = (int)(idx >> 7), q = (int)((idx & 127) << 2);
  int tok = toks[row];
  const float4 v4 = *reinterpret_cast<const float4*>(&emb[((size_t)tok << 9) + q]);
  float v[4] = {v4.x * scale, v4.y * scale, v4.z * scale, v4.w * scale};
  ushort4 h4, l4;
  unsigned short* hp = &h4.x; unsigned short* lp = &l4.x;
  #pragma unroll
  for (int i = 0; i < 4; ++i) {
    unsigned short hb = f2bf(v[i]);
    hp[i] = hb; lp[i] = f2bf(v[i] - bf2f(hb));
  }
  *reinterpret_cast<ushort4*>(&xhi[((size_t)row << 9) + q]) = h4;
  *reinterpret_cast<ushort4*>(&xlo[((size_t)row << 9) + q]) = l4;
}

// ---------------------------------------------------------------------------
// 128x128-tile MFMA GEMM:  C[m,n] = sum_k A[m,k]*B[n,k] + bias[n]
// SPLIT=true: A,B given as hi/lo pairs, 3-term product (~fp32 accuracy).
// LDS tiles 128x64 bf16, XOR chunk swizzle (chunk ^= row&7) -> conflict-free.
// ---------------------------------------------------------------------------
__device__ __forceinline__ void stage_tile(unsigned short* dst,
    const unsigned short* __restrict__ src, size_t row0, int kt, int K, int tid)
{
  #pragma unroll
  for (int j = 0; j < 4; ++j) {
    int chunk = j * 256 + tid;               // 1024 chunks of 16B
    int r = chunk >> 3, c = chunk & 7;
    const int4 v = *reinterpret_cast<const int4*>(
        &src[(row0 + r) * (size_t)K + kt + ((c ^ (r & 7)) << 3)]);
    *reinterpret_cast<int4*>(&dst[r * 64 + (c << 3)]) = v;
  }
}

template <bool SPLIT>
__global__ __launch_bounds__(256) void gemm128(
    const unsigned short* __restrict__ Ahi, const unsigned short* __restrict__ Alo,
    const unsigned short* __restrict__ Bhi, const unsigned short* __restrict__ Blo,
    const float* __restrict__ bias, float* __restrict__ C,
    int K, int ldc, int ncols)
{
  constexpr int PLANES = SPLIT ? 4 : 2;
  __shared__ unsigned short smem[PLANES * 8192];   // 128x64 bf16 per plane
  unsigned short* sAh = smem;
  unsigned short* sAl = SPLIT ? smem + 8192 : nullptr;
  unsigned short* sBh = smem + (SPLIT ? 16384 : 8192);
  unsigned short* sBl = SPLIT ? smem + 24576 : nullptr;

  const int tid = threadIdx.x, lane = tid & 63, wid = tid >> 6;
  const int wm = wid >> 1, wn = wid & 1;
  const size_t m0 = (size_t)blockIdx.x << 7;
  const size_t n0 = (size_t)blockIdx.y << 7;

  f32x4 acc[4][4];
  #pragma unroll
  for (int i = 0; i < 4; ++i)
    #pragma unroll
    for (int j = 0; j < 4; ++j) acc[i][j] = (f32x4){0.f, 0.f, 0.f, 0.f};

  for (int kt = 0; kt < K; kt += 64) {
    if (kt) __syncthreads();
    stage_tile(sAh, Ahi, m0, kt, K, tid);
    if constexpr (SPLIT) stage_tile(sAl, Alo, m0, kt, K, tid);
    stage_tile(sBh, Bhi, n0, kt, K, tid);
    if constexpr (SPLIT) stage_tile(sBl, Blo, n0, kt, K, tid);
    __syncthreads();

    #pragma unroll
    for (int kc = 0; kc < 2; ++kc) {
      const int kg = kc * 4 + (lane >> 4);
      bf16x8 av[4], avl[4], bv[4], bvl[4];
      #pragma unroll
      for (int i = 0; i < 4; ++i) {
        int ra = wm * 64 + i * 16 + (lane & 15);
        int offa = ra * 64 + ((kg ^ (ra & 7)) << 3);
        av[i] = *reinterpret_cast<const bf16x8*>(&sAh[offa]);
        if constexpr (SPLIT) avl[i] = *reinterpret_cast<const bf16x8*>(&sAl[offa]);
        int rb = wn * 64 + i * 16 + (lane & 15);
        int offb = rb * 64 + ((kg ^ (rb & 7)) << 3);
        bv[i] = *reinterpret_cast<const bf16x8*>(&sBh[offb]);
        if constexpr (SPLIT) bvl[i] = *reinterpret_cast<const bf16x8*>(&sBl[offb]);
      }
      #pragma unroll
      for (int i = 0; i < 4; ++i)
        #pragma unroll
        for (int j = 0; j < 4; ++j) {
          acc[i][j] = mfma16(av[i], bv[j], acc[i][j]);
          if constexpr (SPLIT) {
            acc[i][j] = mfma16(avl[i], bv[j], acc[i][j]);
            acc[i][j] = mfma16(av[i], bvl[j], acc[i][j]);
          }
        }
    }
  }

  #pragma unroll
  for (int j = 0; j < 4; ++j) {
    int col = (int)n0 + wn * 64 + j * 16 + (lane & 15);
    float bval = bias[col];
    if (col < ncols) {
      #pragma unroll
      for (int i = 0; i < 4; ++i)
        #pragma unroll
        for (int r = 0; r < 4; ++r) {
          size_t row = m0 + wm * 64 + i * 16 + ((lane >> 4) << 2) + r;
          C[row * (size_t)ldc + col] = acc[i][j][r] + bval;
        }
    }
  }
}

// ---------------------------------------------------------------------------
// Sequential recurrence: h(t) = tanh(h(t-1) @ Wh^T + R[t]), t = 0..127.
// 64 persistent WGs (4 batch-blocks x 16 col-blocks of 32), Wh hi/lo resident
// in LDS (64KB, XOR-swizzled). Per-step device-wide barrier via ws counters.
// Each wave owns one 16x16 quadrant of its WG's 32x32 tile (no LDS reduce).
// h stored as hi/lo bf16 in (S+1)-slot sequence; slot0 = initial hidden.
// ---------------------------------------------------------------------------
__global__ __launch_bounds__(256) void rnn_chain(
    const unsigned short* __restrict__ WhHi, const unsigned short* __restrict__ WhLo,
    const float* __restrict__ R,
    unsigned short* __restrict__ hHi, unsigned short* __restrict__ hLo,
    float* __restrict__ hfin, int* __restrict__ counters, int slot_base)
{
  __shared__ unsigned short wlds[2 * 32 * 512];   // 64 KiB: hi plane, lo plane
  const int tid = threadIdx.x, lane = tid & 63, wid = tid >> 6;
  const int bid = blockIdx.x, mb = bid >> 4, nb = bid & 15;
  const int m0 = mb * 32, n0 = nb * 32;

  // stage Wh rows n0..n0+31 (both planes) with chunk swizzle
  #pragma unroll
  for (int pl = 0; pl < 2; ++pl) {
    const unsigned short* src = pl ? WhLo : WhHi;
    for (int j = 0; j < 8; ++j) {
      int chunk = j * 256 + tid;               // 2048 chunks of 16B per plane
      int r = chunk >> 6, c = chunk & 63;
      const int4 v = *reinterpret_cast<const int4*>(
          &src[((size_t)(n0 + r) << 9) + (c << 3)]);
      *reinterpret_cast<int4*>(&wlds[pl * 16384 + r * 512 + ((c ^ (r & 7)) << 3)]) = v;
    }
  }
  __syncthreads();

  const int ms = wid >> 1, ns = wid & 1;
  const int arow = m0 + ms * 16 + (lane & 15);
  const int brow = ns * 16 + (lane & 15);
  const int k8 = (lane >> 4) << 3;

  for (int t = 0; t < SS; ++t) {
    const size_t abase = (size_t)t << 16;      // t * BH
    f32x4 a0 = {0.f,0.f,0.f,0.f}, a1 = a0, a2 = a0;
    #pragma unroll
    for (int kc = 0; kc < 16; ++kc) {
      int k = kc * 32 + k8;
      size_t ga = abase + ((size_t)arow << 9) + k;
      bf16x8 ahi = *reinterpret_cast<const bf16x8*>(&hHi[ga]);
      bf16x8 alo = *reinterpret_cast<const bf16x8*>(&hLo[ga]);
      int cg = k >> 3;
      int boff = brow * 512 + ((cg ^ (brow & 7)) << 3);
      bf16x8 bhi = *reinterpret_cast<const bf16x8*>(&wlds[boff]);
      bf16x8 blo = *reinterpret_cast<const bf16x8*>(&wlds[16384 + boff]);
      a0 = mfma16(ahi, bhi, a0);
      a1 = mfma16(alo, bhi, a1);
      a2 = mfma16(ahi, blo, a2);
    }
    f32x4 acc = (a0 + a1) + a2;

    #pragma unroll
    for (int r = 0; r < 4; ++r) {
      int row = m0 + ms * 16 + ((lane >> 4) << 2) + r;
      int col = n0 + ns * 16 + (lane & 15);
      float v = acc[r] + R[abase + ((size_t)row << 9) + col];
      float hv = tanhf(v);
      unsigned short hb = f2bf(hv);
      unsigned short lb = f2bf(hv - bf2f(hb));
      size_t oa = abase + (size_t)BH + ((size_t)row << 9) + col;
      hHi[oa] = hb; hLo[oa] = lb;
      if (t == SS - 1) hfin[((size_t)row << 9) + col] = hv;
    }

    if (t < SS - 1) {
      __threadfence();                         // release h writes (agent scope)
      __syncthreads();
      if (tid == 0) {
        int* cp = &counters[slot_base + t];
        atomicAdd(cp, 1);
        int it = 0;
        for (;;) {
          int v;
          if ((++it & 63) == 0) v = atomicAdd(cp, 0);  // coherent fallback poll
          else v = __hip_atomic_load(cp, __ATOMIC_RELAXED, __HIP_MEMORY_SCOPE_AGENT);
          if (v >= 64) break;
          __builtin_amdgcn_s_sleep(2);
        }
        __threadfence();                       // acquire
      }
      __syncthreads();
    }
  }
}

// ---------------------------------------------------------------------------
extern "C" void kernel_launch(void* const* d_in, const int* in_sizes, int n_in,
                              void* d_out, int out_size, void* d_ws, size_t ws_size,
                              hipStream_t stream) {
  const int*   toks   = (const int*)d_in[0];
  const float* hidden = (const float*)d_in[1];
  const float* emb    = (const float*)d_in[2];
  const float* W0     = (const float*)d_in[3];
  const float* b0     = (const float*)d_in[4];
  const float* Wl     = (const float*)d_in[5];
  const float* bl     = (const float*)d_in[6];
  const float* Wout   = (const float*)d_in[7];
  const float* bout   = (const float*)d_in[8];
  float* out = (float*)d_out;
  char* w = (char*)d_ws;

  int* counters = (int*)(w + O_CNT);
  unsigned short* w0h_hi = (unsigned short*)(w + O_W0H_HI);
  unsigned short* w0h_lo = (unsigned short*)(w + O_W0H_LO);
  unsigned short* w0x_hi = (unsigned short*)(w + O_W0X_HI);
  unsigned short* w0x_lo = (unsigned short*)(w + O_W0X_LO);
  unsigned short* w1h_hi = (unsigned short*)(w + O_W1H_HI);
  unsigned short* w1h_lo = (unsigned short*)(w + O_W1H_LO);
  unsigned short* w1x_hi = (unsigned short*)(w + O_W1X_HI);
  unsigned short* w1x_lo = (unsigned short*)(w + O_W1X_LO);
  unsigned short* woutb  = (unsigned short*)(w + O_WOUT);
  float* boutp = (float*)(w + O_BOUT);
  unsigned short* xhi = (unsigned short*)(w + O_R1);
  unsigned short* xlo = xhi + SBH;
  float* Z  = (float*)(w + O_R1);
  float* P0 = (float*)(w + O_R2);
  unsigned short* h1hi = (unsigned short*)(w + O_R2);
  unsigned short* h1lo = h1hi + HSLOT_E;
  unsigned short* h0hi = (unsigned short*)(w + O_R3);
  unsigned short* h0lo = h0hi + HSLOT_E;

  k_setup<<<2048, 256, 0, stream>>>(hidden, W0, Wl, Wout, bout, w);
  k_embed<<<8192, 256, 0, stream>>>(toks, emb, xhi, xlo);

  // P0 = x @ W0x^T + b0
  gemm128<true><<<dim3(128, 4), 256, 0, stream>>>(
      xhi, xlo, w0x_hi, w0x_lo, b0, P0, 512, 512, 512);

  // h0 chain
  rnn_chain<<<64, 256, 0, stream>>>(w0h_hi, w0h_lo, P0, h0hi, h0lo,
                                    out + SBV, counters, 0);

  // h1 slot0 init (after chain0: h1 aliases P0)
  k_h1init<<<256, 256, 0, stream>>>(hidden, h1hi, h1lo);

  // Z = h0seq @ W1x^T + bl   (h0 slots 1..128)
  gemm128<true><<<dim3(128, 4), 256, 0, stream>>>(
      h0hi + BH, h0lo + BH, w1x_hi, w1x_lo, bl, Z, 512, 512, 512);

  // h1 chain
  rnn_chain<<<64, 256, 0, stream>>>(w1h_hi, w1h_lo, Z, h1hi, h1lo,
                                    out + SBV + BH, counters, 128);

  // logits = h1seq(hi) @ Wout^T + bout
  gemm128<false><<<dim3(128, 79), 256, 0, stream>>>(
      h1hi + BH, nullptr, woutb, nullptr, boutp, out, 512, VV, VV);
}